// Round 2
// baseline (54.266 us; speedup 1.0000x reference)
//
#include <hip/hip_runtime.h>

// Problem constants (match reference setup_inputs)
#define NBAGS 64
#define D 512          // feature dim (floats)
#define D4 128         // feature dim in float4
#define NCHUNK 16      // row-chunks per bag

// Pass 1: per-(bag, chunk) partial column sums -> d_ws
// grid = (NBAGS, NCHUNK), block = 256 threads.
// thread t: float4 column (t & 127), row parity (t >> 7).
__global__ void agg_partial_kernel(const float* __restrict__ samples,
                                   const int* __restrict__ counts,
                                   float* __restrict__ partials) {
    const int bag   = blockIdx.x;
    const int chunk = blockIdx.y;

    // Tiny prefix scan over 64 int32 counts (L2-resident; fully unrollable).
    long long off = 0, cnt = 0;
#pragma unroll
    for (int i = 0; i < NBAGS; ++i) {
        long long c = (long long)counts[i];
        off += (i < bag) ? c : 0;
        cnt  = (i == bag) ? c : cnt;
    }
    const long long r0 = off + (cnt * chunk) / NCHUNK;
    const long long r1 = off + (cnt * (chunk + 1)) / NCHUNK;

    const int t    = threadIdx.x;
    const int col  = t & (D4 - 1);
    const int half = t >> 7;

    const float4* __restrict__ src = (const float4*)samples;  // row stride D4

    float4 acc = make_float4(0.f, 0.f, 0.f, 0.f);
    // Each row-parity half handles rows r0+half, r0+half+2, ... (stride 2).
    long long r = r0 + half;
    for (; r + 2 < r1; r += 4) {
        float4 v0 = src[r * D4 + col];
        float4 v1 = src[(r + 2) * D4 + col];
        acc.x += v0.x; acc.y += v0.y; acc.z += v0.z; acc.w += v0.w;
        acc.x += v1.x; acc.y += v1.y; acc.z += v1.z; acc.w += v1.w;
    }
    for (; r < r1; r += 2) {
        float4 v = src[r * D4 + col];
        acc.x += v.x; acc.y += v.y; acc.z += v.z; acc.w += v.w;
    }

    // Combine the two row-parity halves through LDS; half 0 writes out.
    __shared__ float4 lds[D4];
    if (half == 1) lds[col] = acc;
    __syncthreads();
    if (half == 0) {
        float4 o = lds[col];
        acc.x += o.x; acc.y += o.y; acc.z += o.z; acc.w += o.w;
        ((float4*)partials)[(bag * NCHUNK + chunk) * D4 + col] = acc;
    }
}

// Pass 2: reduce NCHUNK partials per bag, scale by 1/count, write output.
// grid = NBAGS, block = D4 threads.
__global__ void agg_reduce_kernel(const float* __restrict__ partials,
                                  const int* __restrict__ counts,
                                  float* __restrict__ out) {
    const int bag = blockIdx.x;
    const int col = threadIdx.x;  // 0..D4-1

    const float4* __restrict__ p = (const float4*)partials;
    float4 acc = make_float4(0.f, 0.f, 0.f, 0.f);
#pragma unroll
    for (int c = 0; c < NCHUNK; ++c) {
        float4 v = p[(bag * NCHUNK + c) * D4 + col];
        acc.x += v.x; acc.y += v.y; acc.z += v.z; acc.w += v.w;
    }
    const float inv = 1.0f / (float)counts[bag];
    acc.x *= inv; acc.y *= inv; acc.z *= inv; acc.w *= inv;
    ((float4*)out)[bag * D4 + col] = acc;
}

extern "C" void kernel_launch(void* const* d_in, const int* in_sizes, int n_in,
                              void* d_out, int out_size, void* d_ws, size_t ws_size,
                              hipStream_t stream) {
    const float* samples  = (const float*)d_in[0];
    const int*   counts   = (const int*)d_in[1];   // harness converts int64 -> int32
    float*       out      = (float*)d_out;
    float*       partials = (float*)d_ws;          // NBAGS*NCHUNK*D floats = 2 MiB

    dim3 grid1(NBAGS, NCHUNK);
    agg_partial_kernel<<<grid1, 256, 0, stream>>>(samples, counts, partials);
    agg_reduce_kernel<<<NBAGS, D4, 0, stream>>>(partials, counts, out);
}